// Round 19
// baseline (166.390 us; speedup 1.0000x reference)
//
#include <hip/hip_runtime.h>

// ---------------------------------------------------------------------------
// MHLP predictor — fused f16 MFMA, R14-body + 3-wave-license experiment.
// R18 confirmed the R16 lock-in (69.4-70.4 us, VGPR 92, stable). Not at a
// BW/compute roofline (VALU 45 / MFMA 13 / HBM 1.3%) -> one clean untried
// experiment: R17 proved the R16 BODY (cross-stage prefetch arrays, ~160
// regs of arrays live) spills under lb(128,3)'s ~170 budget. The R14 BODY
// (same 2-tile ILP, same 69.5 us, but within-stage bf[12] batches only,
// peak array live = 48 regs; measured arch VGPR 88) plausibly fits.
// SINGLE CHANGE from measured R14 source: lb(128,2) -> lb(128,3).
// Pre-committed decision tree:
//   fits  (WRITE ~1 MB): Occ 19->26-30%, dur ~55-62 us.
//   spills(WRITE >10 MB): third cliff confirmation -> revert to R18 config,
//                         declare floor, no further register experiments.
// Predict (fit): VGPR 100-115, Occ 26-30%, VALU 55-62%, Mfma 16-18%,
// absmax 0.003173828 identical.
// ---------------------------------------------------------------------------

using s8v = __attribute__((ext_vector_type(8))) short;
using h8  = __attribute__((ext_vector_type(8))) _Float16;
using h2v = __attribute__((ext_vector_type(2))) _Float16;
using f4  = __attribute__((ext_vector_type(4))) float;

// d_ws u16-unit layout (pre-swizzled f16 weight frags + tables)
#define WF_W1   0        // 12288  (K=75(+bias row 75)->KS=3, NT=8)
#define WF_W2   12288    // 8192   (K=128->KS=4, NT=4)
#define WF_IP   20480    // 12288  (K=64->KS=2, NT=12)
#define WF_OP   32768    // 4096   (K=64->KS=2, NT=4)
#define WF_W3   36864    // 2048   (K=64->KS=2, NT=2)
#define WF_HWE  38912    // 256    (hw_embed f16 [4][64])
#define TQ0     39168    // 256    (q0+bq per hw, f16 [4][64])
#define TK0     39424    // 256    (raw k0)
#define TV0B    39680    // 256    (v0+bv)
#define TV0R    39936    // 256    (raw v0)
#define TBQ     40192    // 64     (q bias f16)

// per-TILE LDS scratch (u16); per wave = 2 tiles
#define PWS     3456     // u16 per tile
#define WPS     6912     // u16 per wave (2 tiles)

__device__ __forceinline__ unsigned short f2h(float f) {
  _Float16 h = (_Float16)f;
  return __builtin_bit_cast(unsigned short, h);
}

__device__ __forceinline__ float dot8(h8 a, h8 b, float acc) {
  const f4 af = __builtin_bit_cast(f4, a), bf = __builtin_bit_cast(f4, b);
#pragma unroll
  for (int u = 0; u < 4; ++u)
    acc = __builtin_amdgcn_fdot2(__builtin_bit_cast(h2v, af[u]),
                                 __builtin_bit_cast(h2v, bf[u]), acc, false);
  return acc;
}

// swizzle W[N][Kreal] row-major f32 -> B-frag f16 layout; optional bias row
// at k == Kreal (folded-bias trick).
__device__ __forceinline__ void swz(const float* __restrict__ W,
                                    const float* __restrict__ bias,
                                    unsigned short* __restrict__ dst,
                                    int Kreal, int KS, int NT, int t, int stride) {
  const int total = KS * NT * 512;
  for (int i = t; i < total; i += stride) {
    const int j = i & 7, ln = (i >> 3) & 63, fr = i >> 9;
    const int nt = fr % NT, ks = fr / NT;
    const int n = nt * 16 + (ln & 15);
    const int k = ks * 32 + (ln >> 4) * 8 + j;
    float v = 0.f;
    if (k < Kreal) v = W[n * Kreal + k];
    else if (bias && k == Kreal) v = bias[n];
    dst[i] = f2h(v);
  }
}

__global__ void k_pre(const float* __restrict__ hwe,
                      const float* __restrict__ W1, const float* __restrict__ b1,
                      const float* __restrict__ W2,
                      const float* __restrict__ ipw, const float* __restrict__ ipb,
                      const float* __restrict__ opw,
                      const float* __restrict__ W3,
                      unsigned short* __restrict__ ws) {
  const int t = blockIdx.x * 256 + threadIdx.x;
  const int stride = gridDim.x * 256;
  swz(W1,  b1,      ws + WF_W1, 75, 3, 8, t, stride);
  swz(W2,  nullptr, ws + WF_W2, 128, 4, 4, t, stride);
  swz(ipw, nullptr, ws + WF_IP, 64, 2, 12, t, stride);
  swz(opw, nullptr, ws + WF_OP, 64, 2, 4, t, stride);
  swz(W3,  nullptr, ws + WF_W3, 64, 2, 2, t, stride);
  for (int i = t; i < 256; i += stride) ws[WF_HWE + i] = f2h(hwe[i]);
  // token-0 qkv tables: qkv0[hw][n] = hw_emb[hw] . in_proj_w[n] (+ bias var.)
  for (int i = t; i < 768; i += stride) {
    const int hw = i / 192, n = i - hw * 192;
    const float* er = hwe + hw * 64;
    const float* wr = ipw + (size_t)n * 64;
    float acc = 0.f;
#pragma unroll 8
    for (int d = 0; d < 64; ++d) acc += er[d] * wr[d];
    if (n < 64)       ws[TQ0  + hw * 64 + n]         = f2h(acc + ipb[n]);
    else if (n < 128) ws[TK0  + hw * 64 + (n - 64)]  = f2h(acc);
    else {            ws[TV0B + hw * 64 + (n - 128)] = f2h(acc + ipb[n]);
                      ws[TV0R + hw * 64 + (n - 128)] = f2h(acc); }
  }
  for (int i = t; i < 64; i += stride) ws[TBQ + i] = f2h(ipb[i]);
}

// ======================= fused: encoder + attention + head =================
__global__ __launch_bounds__(128, 3) void k_fused(
    const int* __restrict__ g_hw,
    const int* __restrict__ g_op, const int* __restrict__ g_wd,
    const float* __restrict__ g_hwe,
    const float* __restrict__ g_b2,
    const float* __restrict__ g_ln1g, const float* __restrict__ g_ln1b,
    const float* __restrict__ g_opb,
    const float* __restrict__ g_ln2g, const float* __restrict__ g_ln2b,
    const float* __restrict__ g_b3,  const float* __restrict__ g_W4,
    const float* __restrict__ g_b4,
    const unsigned short* __restrict__ wsf,   // d_ws base (u16)
    float* __restrict__ g_out) {
  __shared__ __align__(16) unsigned short sm[2 * WPS];
  const int tid = threadIdx.x;
  const int wave = tid >> 6, lane = tid & 63;
  const int quad = lane >> 4, l15 = lane & 15;
  unsigned short* pwA = sm + wave * WPS;
  unsigned short* pwB = pwA + PWS;
  const int m0 = (blockIdx.x * 2 + wave) * 32;   // 4096 blocks x 2 waves x 32

  // ---- index loads (lanes 0..31: A=0..15, B=16..31) + broadcasts ----
  int hwv = 0, c0 = 0, c1 = 0, c2 = 0, c3 = 0, c4 = 0;
  if (lane < 32) {
    const int smp = m0 + lane;
    hwv = g_hw[smp];
    c0 =      g_op[smp * 5 + 0] * 3 + g_wd[smp * 5 + 0];
    c1 = 15 + g_op[smp * 5 + 1] * 3 + g_wd[smp * 5 + 1];
    c2 = 30 + g_op[smp * 5 + 2] * 3 + g_wd[smp * 5 + 2];
    c3 = 45 + g_op[smp * 5 + 3] * 3 + g_wd[smp * 5 + 3];
    c4 = 60 + g_op[smp * 5 + 4] * 3 + g_wd[smp * 5 + 4];
  }
  const int tA0 = __shfl(c0, l15), tA1 = __shfl(c1, l15), tA2 = __shfl(c2, l15);
  const int tA3 = __shfl(c3, l15), tA4 = __shfl(c4, l15);
  const int tB0 = __shfl(c0, 16 + l15), tB1 = __shfl(c1, 16 + l15);
  const int tB2 = __shfl(c2, 16 + l15), tB3 = __shfl(c3, 16 + l15);
  const int tB4 = __shfl(c4, 16 + l15);
  const int hwrowA = __shfl(hwv, l15), hwrowB = __shfl(hwv, 16 + l15);

  // ---- hoisted bias/param loads (shared by both tiles) ----
  float b2v[4], l1gv[4], l1bv[4], opbv[4], l2gv[4], l2bv[4];
#pragma unroll
  for (int nt = 0; nt < 4; ++nt) {
    const int col = nt * 16 + l15;
    b2v[nt] = g_b2[col];  l1gv[nt] = g_ln1g[col]; l1bv[nt] = g_ln1b[col];
    opbv[nt] = g_opb[col]; l2gv[nt] = g_ln2g[col]; l2bv[nt] = g_ln2b[col];
  }
  float b3v[2], w4vv[2];
#pragma unroll
  for (int nt = 0; nt < 2; ++nt) {
    b3v[nt] = g_b3[nt * 16 + l15];
    w4vv[nt] = g_W4[nt * 16 + l15];
  }
  const float b4v = g_b4[0];

  // ---- one-hot via 96-bit membership mask, per tile ----
  h8 aohA[3], aohB[3];
  {
    unsigned wa0 = (1u << tA0) | (1u << tA1);
    unsigned wa1 = 1u << (tA3 - 32);
    unsigned wa2 = 1u << 11;
    const unsigned ma2 = 1u << (tA2 & 31);
    wa0 |= (tA2 < 32) ? ma2 : 0u;  wa1 |= (tA2 >= 32) ? ma2 : 0u;
    const unsigned ma4 = 1u << (tA4 & 31);
    wa1 |= (tA4 < 64) ? ma4 : 0u;  wa2 |= (tA4 >= 64) ? ma4 : 0u;
    unsigned wb0 = (1u << tB0) | (1u << tB1);
    unsigned wb1 = 1u << (tB3 - 32);
    unsigned wb2 = 1u << 11;
    const unsigned mb2 = 1u << (tB2 & 31);
    wb0 |= (tB2 < 32) ? mb2 : 0u;  wb1 |= (tB2 >= 32) ? mb2 : 0u;
    const unsigned mb4 = 1u << (tB4 & 31);
    wb1 |= (tB4 < 64) ? mb4 : 0u;  wb2 |= (tB4 >= 64) ? mb4 : 0u;
#pragma unroll
    for (int ks = 0; ks < 3; ++ks) {
      const unsigned wma = (ks == 0) ? wa0 : (ks == 1) ? wa1 : wa2;
      const unsigned wmb = (ks == 0) ? wb0 : (ks == 1) ? wb1 : wb2;
      const unsigned sa = wma >> (quad * 8), sb = wmb >> (quad * 8);
      s8v a, b;
#pragma unroll
      for (int j = 0; j < 8; ++j) {
        a[j] = ((sa >> j) & 1u) ? (short)0x3C00 : (short)0;
        b[j] = ((sb >> j) & 1u) ? (short)0x3C00 : (short)0;
      }
      aohA[ks] = __builtin_bit_cast(h8, a);
      aohB[ks] = __builtin_bit_cast(h8, b);
    }
  }

  // S1: h = relu(onehot @ [W1;b1]^T) -> h[16][136] in pwA/pwB
  // bf batch loaded ONCE, feeds both tiles' MFMAs.
#pragma unroll
  for (int half = 0; half < 2; ++half) {
    h8 bf[12];
#pragma unroll
    for (int n2 = 0; n2 < 4; ++n2)
#pragma unroll
      for (int ks = 0; ks < 3; ++ks)
        bf[n2 * 3 + ks] = *(const h8*)(wsf + WF_W1 +
            ((ks * 8 + half * 4 + n2) * 64 + lane) * 8);
#pragma unroll
    for (int n2 = 0; n2 < 4; ++n2) {
      f4 accA = {0.f, 0.f, 0.f, 0.f}, accB = {0.f, 0.f, 0.f, 0.f};
#pragma unroll
      for (int ks = 0; ks < 3; ++ks) {
        accA = __builtin_amdgcn_mfma_f32_16x16x32_f16(aohA[ks], bf[n2 * 3 + ks], accA, 0, 0, 0);
        accB = __builtin_amdgcn_mfma_f32_16x16x32_f16(aohB[ks], bf[n2 * 3 + ks], accB, 0, 0, 0);
      }
      const int col = (half * 4 + n2) * 16 + l15;
#pragma unroll
      for (int r = 0; r < 4; ++r) {
        const float vA = accA[r] > 0.f ? accA[r] : 0.f;
        const float vB = accB[r] > 0.f ? accB[r] : 0.f;
        pwA[(quad * 4 + r) * 136 + col] = f2h(vA);
        pwB[(quad * 4 + r) * 136 + col] = f2h(vB);
      }
    }
  }

  // S2: arch = LN1(h @ W2^T + b2); arch f16 -> pw*@0 stride 72,
  // residuals f32 in regs. bf shared across tiles.
  h8 a2A[4], a2B[4];
#pragma unroll
  for (int ks = 0; ks < 4; ++ks) {
    a2A[ks] = *(const h8*)(pwA + l15 * 136 + ks * 32 + quad * 8);
    a2B[ks] = *(const h8*)(pwB + l15 * 136 + ks * 32 + quad * 8);
  }
  float archresA[4][4], archresB[4][4];
  {
    float valA[4][4], valB[4][4];
#pragma unroll
    for (int half = 0; half < 2; ++half) {
      h8 bf[8];
#pragma unroll
      for (int n2 = 0; n2 < 2; ++n2)
#pragma unroll
        for (int ks = 0; ks < 4; ++ks)
          bf[n2 * 4 + ks] = *(const h8*)(wsf + WF_W2 +
              ((ks * 4 + half * 2 + n2) * 64 + lane) * 8);
#pragma unroll
      for (int n2 = 0; n2 < 2; ++n2) {
        f4 accA = {0.f, 0.f, 0.f, 0.f}, accB = {0.f, 0.f, 0.f, 0.f};
#pragma unroll
        for (int ks = 0; ks < 4; ++ks) {
          accA = __builtin_amdgcn_mfma_f32_16x16x32_f16(a2A[ks], bf[n2 * 4 + ks], accA, 0, 0, 0);
          accB = __builtin_amdgcn_mfma_f32_16x16x32_f16(a2B[ks], bf[n2 * 4 + ks], accB, 0, 0, 0);
        }
        const int nt = half * 2 + n2;
#pragma unroll
        for (int r = 0; r < 4; ++r) {
          valA[nt][r] = accA[r] + b2v[nt];
          valB[nt][r] = accB[r] + b2v[nt];
        }
      }
    }
#pragma unroll
    for (int r = 0; r < 4; ++r) {
      float sA = valA[0][r] + valA[1][r] + valA[2][r] + valA[3][r];
      float qA = valA[0][r] * valA[0][r] + valA[1][r] * valA[1][r] +
                 valA[2][r] * valA[2][r] + valA[3][r] * valA[3][r];
      float sB = valB[0][r] + valB[1][r] + valB[2][r] + valB[3][r];
      float qB = valB[0][r] * valB[0][r] + valB[1][r] * valB[1][r] +
                 valB[2][r] * valB[2][r] + valB[3][r] * valB[3][r];
#pragma unroll
      for (int off = 1; off <= 8; off <<= 1) {
        sA += __shfl_xor(sA, off);  qA += __shfl_xor(qA, off);
        sB += __shfl_xor(sB, off);  qB += __shfl_xor(qB, off);
      }
      const float meanA = sA * (1.f / 64.f);
      const float rstdA = rsqrtf(qA * (1.f / 64.f) - meanA * meanA + 1e-5f);
      const float meanB = sB * (1.f / 64.f);
      const float rstdB = rsqrtf(qB * (1.f / 64.f) - meanB * meanB + 1e-5f);
#pragma unroll
      for (int nt = 0; nt < 4; ++nt) {
        const int col = nt * 16 + l15;
        const float xnA = (valA[nt][r] - meanA) * rstdA * l1gv[nt] + l1bv[nt];
        const float xnB = (valB[nt][r] - meanB) * rstdB * l1gv[nt] + l1bv[nt];
        archresA[nt][r] = xnA;
        archresB[nt][r] = xnB;
        pwA[(quad * 4 + r) * 72 + col] = f2h(xnA);
        pwB[(quad * 4 + r) * 72 + col] = f2h(xnB);
      }
    }
  }

  // S3 producer: arch-token q1/k1/v1 -> LDS f16 (Q1@0, K1@1152, V1@2304)
  // per tile; bf shared.
  h8 at1A[2], at1B[2];
#pragma unroll
  for (int ks = 0; ks < 2; ++ks) {
    at1A[ks] = *(const h8*)(pwA + l15 * 72 + ks * 32 + quad * 8);
    at1B[ks] = *(const h8*)(pwB + l15 * 72 + ks * 32 + quad * 8);
  }
#pragma unroll
  for (int hh = 0; hh < 2; ++hh) {
    h8 bf[12];   // [h2][qkv][ks]
#pragma unroll
    for (int h2 = 0; h2 < 2; ++h2) {
      const int h = hh * 2 + h2;
#pragma unroll
      for (int ks = 0; ks < 2; ++ks) {
        bf[h2 * 6 + 0 + ks] = *(const h8*)(wsf + WF_IP + ((ks * 12 + h    ) * 64 + lane) * 8);
        bf[h2 * 6 + 2 + ks] = *(const h8*)(wsf + WF_IP + ((ks * 12 + h + 4) * 64 + lane) * 8);
        bf[h2 * 6 + 4 + ks] = *(const h8*)(wsf + WF_IP + ((ks * 12 + h + 8) * 64 + lane) * 8);
      }
    }
#pragma unroll
    for (int h2 = 0; h2 < 2; ++h2) {
      const int h = hh * 2 + h2;
      f4 aqA = {0.f,0.f,0.f,0.f}, akA = {0.f,0.f,0.f,0.f}, avA = {0.f,0.f,0.f,0.f};
      f4 aqB = {0.f,0.f,0.f,0.f}, akB = {0.f,0.f,0.f,0.f}, avB = {0.f,0.f,0.f,0.f};
#pragma unroll
      for (int ks = 0; ks < 2; ++ks) {
        aqA = __builtin_amdgcn_mfma_f32_16x16x32_f16(at1A[ks], bf[h2 * 6 + 0 + ks], aqA, 0, 0, 0);
        akA = __builtin_amdgcn_mfma_f32_16x16x32_f16(at1A[ks], bf[h2 * 6 + 2 + ks], akA, 0, 0, 0);
        avA = __builtin_amdgcn_mfma_f32_16x16x32_f16(at1A[ks], bf[h2 * 6 + 4 + ks], avA, 0, 0, 0);
        aqB = __builtin_amdgcn_mfma_f32_16x16x32_f16(at1B[ks], bf[h2 * 6 + 0 + ks], aqB, 0, 0, 0);
        akB = __builtin_amdgcn_mfma_f32_16x16x32_f16(at1B[ks], bf[h2 * 6 + 2 + ks], akB, 0, 0, 0);
        avB = __builtin_amdgcn_mfma_f32_16x16x32_f16(at1B[ks], bf[h2 * 6 + 4 + ks], avB, 0, 0, 0);
      }
      const int col = h * 16 + l15;
#pragma unroll
      for (int r = 0; r < 4; ++r) {
        const int row = quad * 4 + r;
        pwA[row * 72 + col]        = f2h(aqA[r]);
        pwA[1152 + row * 72 + col] = f2h(akA[r]);
        pwA[2304 + row * 72 + col] = f2h(avA[r]);
        pwB[row * 72 + col]        = f2h(aqB[r]);
        pwB[1152 + row * 72 + col] = f2h(akB[r]);
        pwB[2304 + row * 72 + col] = f2h(avB[r]);
      }
    }
  }

  // S4 consumer per tile: lane = (sample=l15, head=quad); fdot2 scores.
#pragma unroll
  for (int tile = 0; tile < 2; ++tile) {
    unsigned short* pw = tile ? pwB : pwA;
    const int hwrow = tile ? hwrowB : hwrowA;
    const int qb = quad * 16;
    const unsigned short* q1p = pw + l15 * 72 + qb;
    const h8 q1a = *(const h8*)(q1p),          q1b = *(const h8*)(q1p + 8);
    const h8 k1a = *(const h8*)(q1p + 1152),   k1b = *(const h8*)(q1p + 1160);
    const h8 v1a = *(const h8*)(q1p + 2304),   v1b = *(const h8*)(q1p + 2312);
    const int tb = hwrow * 64 + qb;
    const h8 Q0a = *(const h8*)(wsf + TQ0 + tb),  Q0b = *(const h8*)(wsf + TQ0 + tb + 8);
    const h8 K0a = *(const h8*)(wsf + TK0 + tb),  K0b = *(const h8*)(wsf + TK0 + tb + 8);
    const h8 VBa = *(const h8*)(wsf + TV0B + tb), VBb = *(const h8*)(wsf + TV0B + tb + 8);
    const h8 VRa = *(const h8*)(wsf + TV0R + tb), VRb = *(const h8*)(wsf + TV0R + tb + 8);
    const h8 bqa = *(const h8*)(wsf + TBQ + qb),  bqb = *(const h8*)(wsf + TBQ + qb + 8);
    const h8 dka = k1a - K0a, dkb = k1b - K0b;   // bk cancels
    const float d0 = dot8(Q0a, dka, dot8(Q0b, dkb, 0.f));
    const float d1 = dot8(q1a, dka, dot8(q1b, dkb,
                     dot8(bqa, dka, dot8(bqb, dkb, 0.f))));
    const float a01 = 1.f / (1.f + __expf(-d0 * 0.25f));
    const float a11 = 1.f / (1.f + __expf(-d1 * 0.25f));
    const h8 dva = v1a - VRa, dvb = v1b - VRb;   // bv cancels in dv
    h8 c0a, c0b, c1a, c1b;                       // ctx math in f32
#pragma unroll
    for (int j = 0; j < 8; ++j) {
      const float vb0 = (float)VBa[j], dv0 = (float)dva[j];
      const float vb1 = (float)VBb[j], dv1 = (float)dvb[j];
      c0a[j] = (_Float16)(vb0 + a01 * dv0);
      c0b[j] = (_Float16)(vb1 + a01 * dv1);
      c1a[j] = (_Float16)(vb0 + a11 * dv0);
      c1b[j] = (_Float16)(vb1 + a11 * dv1);
    }
    *(h8*)(pw + l15 * 72 + qb)            = c0a;
    *(h8*)(pw + l15 * 72 + qb + 8)        = c0b;
    *(h8*)(pw + (16 + l15) * 72 + qb)     = c1a;
    *(h8*)(pw + (16 + l15) * 72 + qb + 8) = c1b;
  }

  // S5: out_proj + residual + LN2 + mean-pool -> pool f16 @0, per tile.
  // bf[8] loaded once; tile A finished fully before tile B (caps regs).
  {
    h8 bf[8];
#pragma unroll
    for (int nt = 0; nt < 4; ++nt)
#pragma unroll
      for (int ks = 0; ks < 2; ++ks)
        bf[nt * 2 + ks] = *(const h8*)(wsf + WF_OP + ((ks * 4 + nt) * 64 + lane) * 8);
#pragma unroll
    for (int tile = 0; tile < 2; ++tile) {
      unsigned short* pw = tile ? pwB : pwA;
      h8 ca[2][2];
#pragma unroll
      for (int mt = 0; mt < 2; ++mt)
#pragma unroll
        for (int ks = 0; ks < 2; ++ks)
          ca[mt][ks] = *(const h8*)(pw + (mt * 16 + l15) * 72 + ks * 32 + quad * 8);
      f4 oacc[2][4];
#pragma unroll
      for (int nt = 0; nt < 4; ++nt)
#pragma unroll
        for (int mt = 0; mt < 2; ++mt) {
          f4 acc = {0.f, 0.f, 0.f, 0.f};
          acc = __builtin_amdgcn_mfma_f32_16x16x32_f16(ca[mt][0], bf[nt * 2 + 0], acc, 0, 0, 0);
          acc = __builtin_amdgcn_mfma_f32_16x16x32_f16(ca[mt][1], bf[nt * 2 + 1], acc, 0, 0, 0);
          oacc[mt][nt] = acc;
        }
      float pool[4][4];
#pragma unroll
      for (int mt = 0; mt < 2; ++mt) {
        float val[4][4];
#pragma unroll
        for (int r = 0; r < 4; ++r) {
          if (mt == 0) {
            const int hr = __shfl(hwv, tile * 16 + quad * 4 + r);
#pragma unroll
            for (int nt = 0; nt < 4; ++nt)
              val[nt][r] = oacc[0][nt][r] + opbv[nt] + g_hwe[hr * 64 + nt * 16 + l15];
          } else {
#pragma unroll
            for (int nt = 0; nt < 4; ++nt)
              val[nt][r] = oacc[1][nt][r] + opbv[nt] +
                           (tile ? archresB[nt][r] : archresA[nt][r]);
          }
        }
#pragma unroll
        for (int r = 0; r < 4; ++r) {
          float s = val[0][r] + val[1][r] + val[2][r] + val[3][r];
          float q = val[0][r] * val[0][r] + val[1][r] * val[1][r] +
                    val[2][r] * val[2][r] + val[3][r] * val[3][r];
#pragma unroll
          for (int off = 1; off <= 8; off <<= 1) {
            s += __shfl_xor(s, off);
            q += __shfl_xor(q, off);
          }
          const float mean = s * (1.f / 64.f);
          const float var  = q * (1.f / 64.f) - mean * mean;
          const float rstd = rsqrtf(var + 1e-5f);
#pragma unroll
          for (int nt = 0; nt < 4; ++nt) {
            const float xn = (val[nt][r] - mean) * rstd * l2gv[nt] + l2bv[nt];
            if (mt == 0) pool[nt][r] = 0.5f * xn;
            else         pool[nt][r] += 0.5f * xn;
          }
        }
      }
#pragma unroll
      for (int nt = 0; nt < 4; ++nt)
#pragma unroll
        for (int r = 0; r < 4; ++r)
          pw[(quad * 4 + r) * 72 + nt * 16 + l15] = f2h(pool[nt][r]);
    }
  }

  // S6: head, per tile; bf[4] loaded once.
  {
    h8 bf[4];
#pragma unroll
    for (int nt = 0; nt < 2; ++nt)
#pragma unroll
      for (int ks = 0; ks < 2; ++ks)
        bf[nt * 2 + ks] = *(const h8*)(wsf + WF_W3 + ((ks * 2 + nt) * 64 + lane) * 8);
#pragma unroll
    for (int tile = 0; tile < 2; ++tile) {
      unsigned short* pw = tile ? pwB : pwA;
      h8 pa[2];
#pragma unroll
      for (int ks = 0; ks < 2; ++ks)
        pa[ks] = *(const h8*)(pw + l15 * 72 + ks * 32 + quad * 8);
      float part[4] = {0.f, 0.f, 0.f, 0.f};
#pragma unroll
      for (int nt = 0; nt < 2; ++nt) {
        f4 acc = {0.f, 0.f, 0.f, 0.f};
        acc = __builtin_amdgcn_mfma_f32_16x16x32_f16(pa[0], bf[nt * 2 + 0], acc, 0, 0, 0);
        acc = __builtin_amdgcn_mfma_f32_16x16x32_f16(pa[1], bf[nt * 2 + 1], acc, 0, 0, 0);
#pragma unroll
        for (int r = 0; r < 4; ++r) {
          float y = acc[r] + b3v[nt];
          y = y > 0.f ? y : 0.f;
          part[r] += y * w4vv[nt];
        }
      }
#pragma unroll
      for (int off = 1; off <= 8; off <<= 1)
#pragma unroll
        for (int r = 0; r < 4; ++r)
          part[r] += __shfl_xor(part[r], off);
      if (l15 == 0) {
#pragma unroll
        for (int r = 0; r < 4; ++r)
          g_out[m0 + tile * 16 + quad * 4 + r] = part[r] + b4v;
      }
    }
  }
}

extern "C" void kernel_launch(void* const* d_in, const int* in_sizes, int n_in,
                              void* d_out, int out_size, void* d_ws, size_t ws_size,
                              hipStream_t stream) {
  (void)in_sizes; (void)n_in; (void)out_size; (void)ws_size;
  unsigned short* ws = (unsigned short*)d_ws;

  k_pre<<<64, 256, 0, stream>>>(
      (const float*)d_in[3], (const float*)d_in[4], (const float*)d_in[5],
      (const float*)d_in[6], (const float*)d_in[10], (const float*)d_in[11],
      (const float*)d_in[12], (const float*)d_in[16], ws);

  k_fused<<<4096, 128, 0, stream>>>(
      (const int*)d_in[0],
      (const int*)d_in[1], (const int*)d_in[2],
      (const float*)d_in[3],
      (const float*)d_in[7],
      (const float*)d_in[8], (const float*)d_in[9],
      (const float*)d_in[13],
      (const float*)d_in[14], (const float*)d_in[15],
      (const float*)d_in[17], (const float*)d_in[18],
      (const float*)d_in[19],
      ws, (float*)d_out);
}

// Round 20
// 161.370 us; speedup vs baseline: 1.0311x; 1.0311x over previous
//
#include <hip/hip_runtime.h>

// ---------------------------------------------------------------------------
// MHLP predictor — fused f16 MFMA (FINAL: R16/R18 best config, locked).
// R19 post-mortem (73.3 us, partial spill): R14-body + lb(128,3) clamped
// VGPR to 84 with 6.9 MB scratch writes, Occ only 21% -> THIRD confirmation
// of the register cliff; 3 waves/SIMD never pays. Pre-committed decision:
// revert to R18 config, declare floor.
// Session: 256.5 -> 161.6 us (1.59x). Verified wins kept: single-kernel
// fusion, LDS overlay, sigmoid attention (softmax==sigmoid for 2 tokens),
// bitmask one-hot, token-0 qkv table precompute, batched frag loads,
// 2-tile-per-wave ILP. Falsified with counters: barrier staging, bias LDS
// table, occupancy pins (x3: R5/R17/R19), deep cross-stage prefetch.
// Remaining profile (VALU 45 / MFMA 13 / HBM 1.3 / Occ 19%) is a latency
// floor at the 2-waves/SIMD register cliff; total-minus-kernel ~92 us is
// harness-fixed (invariant across 19 variants).
// Predict: VGPR 92, WRITE ~1 MB, Occ ~19%, k_fused ~69-70 us,
// total ~162-166 us, absmax 0.003173828.
// ---------------------------------------------------------------------------

using s8v = __attribute__((ext_vector_type(8))) short;
using h8  = __attribute__((ext_vector_type(8))) _Float16;
using h2v = __attribute__((ext_vector_type(2))) _Float16;
using f4  = __attribute__((ext_vector_type(4))) float;

// d_ws u16-unit layout (pre-swizzled f16 weight frags + tables)
#define WF_W1   0        // 12288  (K=75(+bias row 75)->KS=3, NT=8)
#define WF_W2   12288    // 8192   (K=128->KS=4, NT=4)
#define WF_IP   20480    // 12288  (K=64->KS=2, NT=12)
#define WF_OP   32768    // 4096   (K=64->KS=2, NT=4)
#define WF_W3   36864    // 2048   (K=64->KS=2, NT=2)
#define WF_HWE  38912    // 256    (hw_embed f16 [4][64])
#define TQ0     39168    // 256    (q0+bq per hw, f16 [4][64])
#define TK0     39424    // 256    (raw k0)
#define TV0B    39680    // 256    (v0+bv)
#define TV0R    39936    // 256    (raw v0)
#define TBQ     40192    // 64     (q bias f16)

// per-TILE LDS scratch (u16); per wave = 2 tiles
#define PWS     3456     // u16 per tile
#define WPS     6912     // u16 per wave (2 tiles)

__device__ __forceinline__ unsigned short f2h(float f) {
  _Float16 h = (_Float16)f;
  return __builtin_bit_cast(unsigned short, h);
}

__device__ __forceinline__ float dot8(h8 a, h8 b, float acc) {
  const f4 af = __builtin_bit_cast(f4, a), bf = __builtin_bit_cast(f4, b);
#pragma unroll
  for (int u = 0; u < 4; ++u)
    acc = __builtin_amdgcn_fdot2(__builtin_bit_cast(h2v, af[u]),
                                 __builtin_bit_cast(h2v, bf[u]), acc, false);
  return acc;
}

// swizzle W[N][Kreal] row-major f32 -> B-frag f16 layout; optional bias row
// at k == Kreal (folded-bias trick).
__device__ __forceinline__ void swz(const float* __restrict__ W,
                                    const float* __restrict__ bias,
                                    unsigned short* __restrict__ dst,
                                    int Kreal, int KS, int NT, int t, int stride) {
  const int total = KS * NT * 512;
  for (int i = t; i < total; i += stride) {
    const int j = i & 7, ln = (i >> 3) & 63, fr = i >> 9;
    const int nt = fr % NT, ks = fr / NT;
    const int n = nt * 16 + (ln & 15);
    const int k = ks * 32 + (ln >> 4) * 8 + j;
    float v = 0.f;
    if (k < Kreal) v = W[n * Kreal + k];
    else if (bias && k == Kreal) v = bias[n];
    dst[i] = f2h(v);
  }
}

__global__ void k_pre(const float* __restrict__ hwe,
                      const float* __restrict__ W1, const float* __restrict__ b1,
                      const float* __restrict__ W2,
                      const float* __restrict__ ipw, const float* __restrict__ ipb,
                      const float* __restrict__ opw,
                      const float* __restrict__ W3,
                      unsigned short* __restrict__ ws) {
  const int t = blockIdx.x * 256 + threadIdx.x;
  const int stride = gridDim.x * 256;
  swz(W1,  b1,      ws + WF_W1, 75, 3, 8, t, stride);
  swz(W2,  nullptr, ws + WF_W2, 128, 4, 4, t, stride);
  swz(ipw, nullptr, ws + WF_IP, 64, 2, 12, t, stride);
  swz(opw, nullptr, ws + WF_OP, 64, 2, 4, t, stride);
  swz(W3,  nullptr, ws + WF_W3, 64, 2, 2, t, stride);
  for (int i = t; i < 256; i += stride) ws[WF_HWE + i] = f2h(hwe[i]);
  // token-0 qkv tables: qkv0[hw][n] = hw_emb[hw] . in_proj_w[n] (+ bias var.)
  for (int i = t; i < 768; i += stride) {
    const int hw = i / 192, n = i - hw * 192;
    const float* er = hwe + hw * 64;
    const float* wr = ipw + (size_t)n * 64;
    float acc = 0.f;
#pragma unroll 8
    for (int d = 0; d < 64; ++d) acc += er[d] * wr[d];
    if (n < 64)       ws[TQ0  + hw * 64 + n]         = f2h(acc + ipb[n]);
    else if (n < 128) ws[TK0  + hw * 64 + (n - 64)]  = f2h(acc);
    else {            ws[TV0B + hw * 64 + (n - 128)] = f2h(acc + ipb[n]);
                      ws[TV0R + hw * 64 + (n - 128)] = f2h(acc); }
  }
  for (int i = t; i < 64; i += stride) ws[TBQ + i] = f2h(ipb[i]);
}

// ======================= fused: encoder + attention + head =================
__global__ __launch_bounds__(128, 2) void k_fused(
    const int* __restrict__ g_hw,
    const int* __restrict__ g_op, const int* __restrict__ g_wd,
    const float* __restrict__ g_hwe,
    const float* __restrict__ g_b2,
    const float* __restrict__ g_ln1g, const float* __restrict__ g_ln1b,
    const float* __restrict__ g_opb,
    const float* __restrict__ g_ln2g, const float* __restrict__ g_ln2b,
    const float* __restrict__ g_b3,  const float* __restrict__ g_W4,
    const float* __restrict__ g_b4,
    const unsigned short* __restrict__ wsf,   // d_ws base (u16)
    float* __restrict__ g_out) {
  __shared__ __align__(16) unsigned short sm[2 * WPS];
  const int tid = threadIdx.x;
  const int wave = tid >> 6, lane = tid & 63;
  const int quad = lane >> 4, l15 = lane & 15;
  unsigned short* pwA = sm + wave * WPS;
  unsigned short* pwB = pwA + PWS;
  const int m0 = (blockIdx.x * 2 + wave) * 32;   // 4096 blocks x 2 waves x 32

  // ---- index loads FIRST (oldest in vmcnt queue -> no drain) ----
  int hwv = 0, c0 = 0, c1 = 0, c2 = 0, c3 = 0, c4 = 0;
  if (lane < 32) {
    const int smp = m0 + lane;
    hwv = g_hw[smp];
    c0 =      g_op[smp * 5 + 0] * 3 + g_wd[smp * 5 + 0];
    c1 = 15 + g_op[smp * 5 + 1] * 3 + g_wd[smp * 5 + 1];
    c2 = 30 + g_op[smp * 5 + 2] * 3 + g_wd[smp * 5 + 2];
    c3 = 45 + g_op[smp * 5 + 3] * 3 + g_wd[smp * 5 + 3];
    c4 = 60 + g_op[smp * 5 + 4] * 3 + g_wd[smp * 5 + 4];
  }

  // ---- PREFETCH: S1 (24) + S2 (16) frag loads (behind index loads) ----
  h8 bf1[24];
#pragma unroll
  for (int half = 0; half < 2; ++half)
#pragma unroll
    for (int n2 = 0; n2 < 4; ++n2)
#pragma unroll
      for (int ks = 0; ks < 3; ++ks)
        bf1[half * 12 + n2 * 3 + ks] = *(const h8*)(wsf + WF_W1 +
            ((ks * 8 + half * 4 + n2) * 64 + lane) * 8);
  h8 bf2[16];
#pragma unroll
  for (int half = 0; half < 2; ++half)
#pragma unroll
    for (int n2 = 0; n2 < 2; ++n2)
#pragma unroll
      for (int ks = 0; ks < 4; ++ks)
        bf2[half * 8 + n2 * 4 + ks] = *(const h8*)(wsf + WF_W2 +
            ((ks * 4 + half * 2 + n2) * 64 + lane) * 8);

  // ---- hoisted bias/param loads (overlap prologue) ----
  float b2v[4], l1gv[4], l1bv[4], opbv[4], l2gv[4], l2bv[4];
#pragma unroll
  for (int nt = 0; nt < 4; ++nt) {
    const int col = nt * 16 + l15;
    b2v[nt] = g_b2[col];  l1gv[nt] = g_ln1g[col]; l1bv[nt] = g_ln1b[col];
    opbv[nt] = g_opb[col]; l2gv[nt] = g_ln2g[col]; l2bv[nt] = g_ln2b[col];
  }
  float b3v[2], w4vv[2];
#pragma unroll
  for (int nt = 0; nt < 2; ++nt) {
    b3v[nt] = g_b3[nt * 16 + l15];
    w4vv[nt] = g_W4[nt * 16 + l15];
  }
  const float b4v = g_b4[0];

  // ---- broadcasts (wait only on index loads = oldest) ----
  const int tA0 = __shfl(c0, l15), tA1 = __shfl(c1, l15), tA2 = __shfl(c2, l15);
  const int tA3 = __shfl(c3, l15), tA4 = __shfl(c4, l15);
  const int tB0 = __shfl(c0, 16 + l15), tB1 = __shfl(c1, 16 + l15);
  const int tB2 = __shfl(c2, 16 + l15), tB3 = __shfl(c3, 16 + l15);
  const int tB4 = __shfl(c4, 16 + l15);
  const int hwrowA = __shfl(hwv, l15), hwrowB = __shfl(hwv, 16 + l15);

  // ---- one-hot via 96-bit membership mask, per tile ----
  h8 aohA[3], aohB[3];
  {
    unsigned wa0 = (1u << tA0) | (1u << tA1);
    unsigned wa1 = 1u << (tA3 - 32);
    unsigned wa2 = 1u << 11;
    const unsigned ma2 = 1u << (tA2 & 31);
    wa0 |= (tA2 < 32) ? ma2 : 0u;  wa1 |= (tA2 >= 32) ? ma2 : 0u;
    const unsigned ma4 = 1u << (tA4 & 31);
    wa1 |= (tA4 < 64) ? ma4 : 0u;  wa2 |= (tA4 >= 64) ? ma4 : 0u;
    unsigned wb0 = (1u << tB0) | (1u << tB1);
    unsigned wb1 = 1u << (tB3 - 32);
    unsigned wb2 = 1u << 11;
    const unsigned mb2 = 1u << (tB2 & 31);
    wb0 |= (tB2 < 32) ? mb2 : 0u;  wb1 |= (tB2 >= 32) ? mb2 : 0u;
    const unsigned mb4 = 1u << (tB4 & 31);
    wb1 |= (tB4 < 64) ? mb4 : 0u;  wb2 |= (tB4 >= 64) ? mb4 : 0u;
#pragma unroll
    for (int ks = 0; ks < 3; ++ks) {
      const unsigned wma = (ks == 0) ? wa0 : (ks == 1) ? wa1 : wa2;
      const unsigned wmb = (ks == 0) ? wb0 : (ks == 1) ? wb1 : wb2;
      const unsigned sa = wma >> (quad * 8), sb = wmb >> (quad * 8);
      s8v a, b;
#pragma unroll
      for (int j = 0; j < 8; ++j) {
        a[j] = ((sa >> j) & 1u) ? (short)0x3C00 : (short)0;
        b[j] = ((sb >> j) & 1u) ? (short)0x3C00 : (short)0;
      }
      aohA[ks] = __builtin_bit_cast(h8, a);
      aohB[ks] = __builtin_bit_cast(h8, b);
    }
  }

  // S1: h = relu(onehot @ [W1;b1]^T) -> h[16][136] in pwA/pwB (bf1 ready)
#pragma unroll
  for (int half = 0; half < 2; ++half) {
#pragma unroll
    for (int n2 = 0; n2 < 4; ++n2) {
      f4 accA = {0.f, 0.f, 0.f, 0.f}, accB = {0.f, 0.f, 0.f, 0.f};
#pragma unroll
      for (int ks = 0; ks < 3; ++ks) {
        const h8 bf = bf1[half * 12 + n2 * 3 + ks];
        accA = __builtin_amdgcn_mfma_f32_16x16x32_f16(aohA[ks], bf, accA, 0, 0, 0);
        accB = __builtin_amdgcn_mfma_f32_16x16x32_f16(aohB[ks], bf, accB, 0, 0, 0);
      }
      const int col = (half * 4 + n2) * 16 + l15;
#pragma unroll
      for (int r = 0; r < 4; ++r) {
        const float vA = accA[r] > 0.f ? accA[r] : 0.f;
        const float vB = accB[r] > 0.f ? accB[r] : 0.f;
        pwA[(quad * 4 + r) * 136 + col] = f2h(vA);
        pwB[(quad * 4 + r) * 136 + col] = f2h(vB);
      }
    }
  }

  // a2 frag reads (LDS)
  h8 a2A[4], a2B[4];
#pragma unroll
  for (int ks = 0; ks < 4; ++ks) {
    a2A[ks] = *(const h8*)(pwA + l15 * 136 + ks * 32 + quad * 8);
    a2B[ks] = *(const h8*)(pwB + l15 * 136 + ks * 32 + quad * 8);
  }

  // ---- PREFETCH: S3 frags (24) before S2 compute ----
  h8 bf3[24];   // [hh][h2][qkv][ks]
#pragma unroll
  for (int hh = 0; hh < 2; ++hh)
#pragma unroll
    for (int h2 = 0; h2 < 2; ++h2) {
      const int h = hh * 2 + h2;
#pragma unroll
      for (int ks = 0; ks < 2; ++ks) {
        bf3[hh * 12 + h2 * 6 + 0 + ks] = *(const h8*)(wsf + WF_IP + ((ks * 12 + h    ) * 64 + lane) * 8);
        bf3[hh * 12 + h2 * 6 + 2 + ks] = *(const h8*)(wsf + WF_IP + ((ks * 12 + h + 4) * 64 + lane) * 8);
        bf3[hh * 12 + h2 * 6 + 4 + ks] = *(const h8*)(wsf + WF_IP + ((ks * 12 + h + 8) * 64 + lane) * 8);
      }
    }

  // S2: arch = LN1(h @ W2^T + b2) (bf2 ready); arch f16 -> pw*@0 stride 72,
  // residuals f32 in regs.
  float archresA[4][4], archresB[4][4];
  {
    float valA[4][4], valB[4][4];
#pragma unroll
    for (int half = 0; half < 2; ++half)
#pragma unroll
      for (int n2 = 0; n2 < 2; ++n2) {
        f4 accA = {0.f, 0.f, 0.f, 0.f}, accB = {0.f, 0.f, 0.f, 0.f};
#pragma unroll
        for (int ks = 0; ks < 4; ++ks) {
          const h8 bf = bf2[half * 8 + n2 * 4 + ks];
          accA = __builtin_amdgcn_mfma_f32_16x16x32_f16(a2A[ks], bf, accA, 0, 0, 0);
          accB = __builtin_amdgcn_mfma_f32_16x16x32_f16(a2B[ks], bf, accB, 0, 0, 0);
        }
        const int nt = half * 2 + n2;
#pragma unroll
        for (int r = 0; r < 4; ++r) {
          valA[nt][r] = accA[r] + b2v[nt];
          valB[nt][r] = accB[r] + b2v[nt];
        }
      }
#pragma unroll
    for (int r = 0; r < 4; ++r) {
      float sA = valA[0][r] + valA[1][r] + valA[2][r] + valA[3][r];
      float qA = valA[0][r] * valA[0][r] + valA[1][r] * valA[1][r] +
                 valA[2][r] * valA[2][r] + valA[3][r] * valA[3][r];
      float sB = valB[0][r] + valB[1][r] + valB[2][r] + valB[3][r];
      float qB = valB[0][r] * valB[0][r] + valB[1][r] * valB[1][r] +
                 valB[2][r] * valB[2][r] + valB[3][r] * valB[3][r];
#pragma unroll
      for (int off = 1; off <= 8; off <<= 1) {
        sA += __shfl_xor(sA, off);  qA += __shfl_xor(qA, off);
        sB += __shfl_xor(sB, off);  qB += __shfl_xor(qB, off);
      }
      const float meanA = sA * (1.f / 64.f);
      const float rstdA = rsqrtf(qA * (1.f / 64.f) - meanA * meanA + 1e-5f);
      const float meanB = sB * (1.f / 64.f);
      const float rstdB = rsqrtf(qB * (1.f / 64.f) - meanB * meanB + 1e-5f);
#pragma unroll
      for (int nt = 0; nt < 4; ++nt) {
        const int col = nt * 16 + l15;
        const float xnA = (valA[nt][r] - meanA) * rstdA * l1gv[nt] + l1bv[nt];
        const float xnB = (valB[nt][r] - meanB) * rstdB * l1gv[nt] + l1bv[nt];
        archresA[nt][r] = xnA;
        archresB[nt][r] = xnB;
        pwA[(quad * 4 + r) * 72 + col] = f2h(xnA);
        pwB[(quad * 4 + r) * 72 + col] = f2h(xnB);
      }
    }
  }

  // at1 reads (LDS)
  h8 at1A[2], at1B[2];
#pragma unroll
  for (int ks = 0; ks < 2; ++ks) {
    at1A[ks] = *(const h8*)(pwA + l15 * 72 + ks * 32 + quad * 8);
    at1B[ks] = *(const h8*)(pwB + l15 * 72 + ks * 32 + quad * 8);
  }

  // ---- PREFETCH: S5 (8) + S6 (4) frags before S3 compute ----
  h8 bf5[8];
#pragma unroll
  for (int nt = 0; nt < 4; ++nt)
#pragma unroll
    for (int ks = 0; ks < 2; ++ks)
      bf5[nt * 2 + ks] = *(const h8*)(wsf + WF_OP + ((ks * 4 + nt) * 64 + lane) * 8);
  h8 bf6[4];
#pragma unroll
  for (int nt = 0; nt < 2; ++nt)
#pragma unroll
    for (int ks = 0; ks < 2; ++ks)
      bf6[nt * 2 + ks] = *(const h8*)(wsf + WF_W3 + ((ks * 2 + nt) * 64 + lane) * 8);

  // S3 producer: arch-token q1/k1/v1 -> LDS f16 (Q1@0, K1@1152, V1@2304)
  // per tile (bf3 ready).
#pragma unroll
  for (int hh = 0; hh < 2; ++hh)
#pragma unroll
    for (int h2 = 0; h2 < 2; ++h2) {
      const int h = hh * 2 + h2;
      f4 aqA = {0.f,0.f,0.f,0.f}, akA = {0.f,0.f,0.f,0.f}, avA = {0.f,0.f,0.f,0.f};
      f4 aqB = {0.f,0.f,0.f,0.f}, akB = {0.f,0.f,0.f,0.f}, avB = {0.f,0.f,0.f,0.f};
#pragma unroll
      for (int ks = 0; ks < 2; ++ks) {
        const h8 bq = bf3[hh * 12 + h2 * 6 + 0 + ks];
        const h8 bk = bf3[hh * 12 + h2 * 6 + 2 + ks];
        const h8 bv = bf3[hh * 12 + h2 * 6 + 4 + ks];
        aqA = __builtin_amdgcn_mfma_f32_16x16x32_f16(at1A[ks], bq, aqA, 0, 0, 0);
        akA = __builtin_amdgcn_mfma_f32_16x16x32_f16(at1A[ks], bk, akA, 0, 0, 0);
        avA = __builtin_amdgcn_mfma_f32_16x16x32_f16(at1A[ks], bv, avA, 0, 0, 0);
        aqB = __builtin_amdgcn_mfma_f32_16x16x32_f16(at1B[ks], bq, aqB, 0, 0, 0);
        akB = __builtin_amdgcn_mfma_f32_16x16x32_f16(at1B[ks], bk, akB, 0, 0, 0);
        avB = __builtin_amdgcn_mfma_f32_16x16x32_f16(at1B[ks], bv, avB, 0, 0, 0);
      }
      const int col = h * 16 + l15;
#pragma unroll
      for (int r = 0; r < 4; ++r) {
        const int row = quad * 4 + r;
        pwA[row * 72 + col]        = f2h(aqA[r]);
        pwA[1152 + row * 72 + col] = f2h(akA[r]);
        pwA[2304 + row * 72 + col] = f2h(avA[r]);
        pwB[row * 72 + col]        = f2h(aqB[r]);
        pwB[1152 + row * 72 + col] = f2h(akB[r]);
        pwB[2304 + row * 72 + col] = f2h(avB[r]);
      }
    }

  // S4 consumer per tile: lane = (sample=l15, head=quad); fdot2 scores.
#pragma unroll
  for (int tile = 0; tile < 2; ++tile) {
    unsigned short* pw = tile ? pwB : pwA;
    const int hwrow = tile ? hwrowB : hwrowA;
    const int qb = quad * 16;
    const unsigned short* q1p = pw + l15 * 72 + qb;
    const h8 q1a = *(const h8*)(q1p),          q1b = *(const h8*)(q1p + 8);
    const h8 k1a = *(const h8*)(q1p + 1152),   k1b = *(const h8*)(q1p + 1160);
    const h8 v1a = *(const h8*)(q1p + 2304),   v1b = *(const h8*)(q1p + 2312);
    const int tb = hwrow * 64 + qb;
    const h8 Q0a = *(const h8*)(wsf + TQ0 + tb),  Q0b = *(const h8*)(wsf + TQ0 + tb + 8);
    const h8 K0a = *(const h8*)(wsf + TK0 + tb),  K0b = *(const h8*)(wsf + TK0 + tb + 8);
    const h8 VBa = *(const h8*)(wsf + TV0B + tb), VBb = *(const h8*)(wsf + TV0B + tb + 8);
    const h8 VRa = *(const h8*)(wsf + TV0R + tb), VRb = *(const h8*)(wsf + TV0R + tb + 8);
    const h8 bqa = *(const h8*)(wsf + TBQ + qb),  bqb = *(const h8*)(wsf + TBQ + qb + 8);
    const h8 dka = k1a - K0a, dkb = k1b - K0b;   // bk cancels
    const float d0 = dot8(Q0a, dka, dot8(Q0b, dkb, 0.f));
    const float d1 = dot8(q1a, dka, dot8(q1b, dkb,
                     dot8(bqa, dka, dot8(bqb, dkb, 0.f))));
    const float a01 = 1.f / (1.f + __expf(-d0 * 0.25f));
    const float a11 = 1.f / (1.f + __expf(-d1 * 0.25f));
    const h8 dva = v1a - VRa, dvb = v1b - VRb;   // bv cancels in dv
    h8 c0a, c0b, c1a, c1b;                       // ctx math in f32
#pragma unroll
    for (int j = 0; j < 8; ++j) {
      const float vb0 = (float)VBa[j], dv0 = (float)dva[j];
      const float vb1 = (float)VBb[j], dv1 = (float)dvb[j];
      c0a[j] = (_Float16)(vb0 + a01 * dv0);
      c0b[j] = (_Float16)(vb1 + a01 * dv1);
      c1a[j] = (_Float16)(vb0 + a11 * dv0);
      c1b[j] = (_Float16)(vb1 + a11 * dv1);
    }
    *(h8*)(pw + l15 * 72 + qb)            = c0a;
    *(h8*)(pw + l15 * 72 + qb + 8)        = c0b;
    *(h8*)(pw + (16 + l15) * 72 + qb)     = c1a;
    *(h8*)(pw + (16 + l15) * 72 + qb + 8) = c1b;
  }

  // S5: out_proj + residual + LN2 + mean-pool -> pool f16 @0, per tile
  // (bf5 ready; tile A finished before B to cap regs).
#pragma unroll
  for (int tile = 0; tile < 2; ++tile) {
    unsigned short* pw = tile ? pwB : pwA;
    h8 ca[2][2];
#pragma unroll
    for (int mt = 0; mt < 2; ++mt)
#pragma unroll
      for (int ks = 0; ks < 2; ++ks)
        ca[mt][ks] = *(const h8*)(pw + (mt * 16 + l15) * 72 + ks * 32 + quad * 8);
    f4 oacc[2][4];
#pragma unroll
    for (int nt = 0; nt < 4; ++nt)
#pragma unroll
      for (int mt = 0; mt < 2; ++mt) {
        f4 acc = {0.f, 0.f, 0.f, 0.f};
        acc = __builtin_amdgcn_mfma_f32_16x16x32_f16(ca[mt][0], bf5[nt * 2 + 0], acc, 0, 0, 0);
        acc = __builtin_amdgcn_mfma_f32_16x16x32_f16(ca[mt][1], bf5[nt * 2 + 1], acc, 0, 0, 0);
        oacc[mt][nt] = acc;
      }
    float pool[4][4];
#pragma unroll
    for (int mt = 0; mt < 2; ++mt) {
      float val[4][4];
#pragma unroll
      for (int r = 0; r < 4; ++r) {
        if (mt == 0) {
          const int hr = __shfl(hwv, tile * 16 + quad * 4 + r);
#pragma unroll
          for (int nt = 0; nt < 4; ++nt)
            val[nt][r] = oacc[0][nt][r] + opbv[nt] + g_hwe[hr * 64 + nt * 16 + l15];
        } else {
#pragma unroll
          for (int nt = 0; nt < 4; ++nt)
            val[nt][r] = oacc[1][nt][r] + opbv[nt] +
                         (tile ? archresB[nt][r] : archresA[nt][r]);
        }
      }
#pragma unroll
      for (int r = 0; r < 4; ++r) {
        float s = val[0][r] + val[1][r] + val[2][r] + val[3][r];
        float q = val[0][r] * val[0][r] + val[1][r] * val[1][r] +
                  val[2][r] * val[2][r] + val[3][r] * val[3][r];
#pragma unroll
        for (int off = 1; off <= 8; off <<= 1) {
          s += __shfl_xor(s, off);
          q += __shfl_xor(q, off);
        }
        const float mean = s * (1.f / 64.f);
        const float var  = q * (1.f / 64.f) - mean * mean;
        const float rstd = rsqrtf(var + 1e-5f);
#pragma unroll
        for (int nt = 0; nt < 4; ++nt) {
          const float xn = (val[nt][r] - mean) * rstd * l2gv[nt] + l2bv[nt];
          if (mt == 0) pool[nt][r] = 0.5f * xn;
          else         pool[nt][r] += 0.5f * xn;
        }
      }
    }
#pragma unroll
    for (int nt = 0; nt < 4; ++nt)
#pragma unroll
      for (int r = 0; r < 4; ++r)
        pw[(quad * 4 + r) * 72 + nt * 16 + l15] = f2h(pool[nt][r]);
  }

  // S6: head, per tile (bf6 ready).
#pragma unroll
  for (int tile = 0; tile < 2; ++tile) {
    unsigned short* pw = tile ? pwB : pwA;
    h8 pa[2];
#pragma unroll
    for (int ks = 0; ks < 2; ++ks)
      pa[ks] = *(const h8*)(pw + l15 * 72 + ks * 32 + quad * 8);
    float part[4] = {0.f, 0.f, 0.f, 0.f};
#pragma unroll
    for (int nt = 0; nt < 2; ++nt) {
      f4 acc = {0.f, 0.f, 0.f, 0.f};
      acc = __builtin_amdgcn_mfma_f32_16x16x32_f16(pa[0], bf6[nt * 2 + 0], acc, 0, 0, 0);
      acc = __builtin_amdgcn_mfma_f32_16x16x32_f16(pa[1], bf6[nt * 2 + 1], acc, 0, 0, 0);
#pragma unroll
      for (int r = 0; r < 4; ++r) {
        float y = acc[r] + b3v[nt];
        y = y > 0.f ? y : 0.f;
        part[r] += y * w4vv[nt];
      }
    }
#pragma unroll
    for (int off = 1; off <= 8; off <<= 1)
#pragma unroll
      for (int r = 0; r < 4; ++r)
        part[r] += __shfl_xor(part[r], off);
    if (l15 == 0) {
#pragma unroll
      for (int r = 0; r < 4; ++r)
        g_out[m0 + tile * 16 + quad * 4 + r] = part[r] + b4v;
    }
  }
}

extern "C" void kernel_launch(void* const* d_in, const int* in_sizes, int n_in,
                              void* d_out, int out_size, void* d_ws, size_t ws_size,
                              hipStream_t stream) {
  (void)in_sizes; (void)n_in; (void)out_size; (void)ws_size;
  unsigned short* ws = (unsigned short*)d_ws;

  k_pre<<<64, 256, 0, stream>>>(
      (const float*)d_in[3], (const float*)d_in[4], (const float*)d_in[5],
      (const float*)d_in[6], (const float*)d_in[10], (const float*)d_in[11],
      (const float*)d_in[12], (const float*)d_in[16], ws);

  k_fused<<<4096, 128, 0, stream>>>(
      (const int*)d_in[0],
      (const int*)d_in[1], (const int*)d_in[2],
      (const float*)d_in[3],
      (const float*)d_in[7],
      (const float*)d_in[8], (const float*)d_in[9],
      (const float*)d_in[13],
      (const float*)d_in[14], (const float*)d_in[15],
      (const float*)d_in[17], (const float*)d_in[18],
      (const float*)d_in[19],
      ws, (float*)d_out);
}